// Round 3
// baseline (729.782 us; speedup 1.0000x reference)
//
#include <hip/hip_runtime.h>

static constexpr int NN  = 4194304;   // N
static constexpr int NB  = 4096;      // blocks; NB * TPB * 4 rows == NN
static constexpr int TPB = 256;

// ---------------------------------------------------------------------------
// Fused kernel: each thread handles ONE group of 4 rows (max waves in flight,
// shortest dependency chain per wave — latency hiding via TLP not ILP).
// Per-block partials -> d_ws; last finished block (device-scope counter)
// reduces the partials and writes the scalar. No second launch.
// ---------------------------------------------------------------------------
__global__ __launch_bounds__(256) void pfl_fused(
    const float* __restrict__ pp,   // pred_prices [N]
    const float* __restrict__ pa,   // pred_actions [N,3]
    const float* __restrict__ tp,   // tgt_prices [N]
    const int*   __restrict__ ta,   // tgt_actions [N] (int32)
    float* __restrict__ bsum,       // [3*NB] per-block partials
    unsigned* __restrict__ counter, // zeroed by memset node
    float* __restrict__ out)
{
    const int tid = threadIdx.x;
    const int bid = blockIdx.x;
    const int g   = bid * TPB + tid;   // group of 4 rows
    const int i   = g * 4;

    const float4* pp4 = (const float4*)pp;
    const float4* tp4 = (const float4*)tp;
    const float4* pa4 = (const float4*)pa;
    const int4*   ta4 = (const int4*)ta;

    // ---- loads (all issued up front) -----------------------------------
    float4 p  = pp4[g];
    float4 t  = tp4[g];
    int4   a  = ta4[g];
    float4 A0 = pa4[3*g + 0];
    float4 A1 = pa4[3*g + 1];
    float4 A2 = pa4[3*g + 2];
    float tm1 = (i > 0)      ? tp[i - 1] : 0.f;   // L1 hits
    float tnx = (i + 4 < NN) ? tp[i + 4] : 0.f;

    float tv[6] = {tm1, t.x, t.y, t.z, t.w, tnx};
    float pv[4] = {p.x, p.y, p.z, p.w};
    float rows[4][3] = {{A0.x, A0.y, A0.z},
                        {A0.w, A1.x, A1.y},
                        {A1.z, A1.w, A2.x},
                        {A2.y, A2.z, A2.w}};
    int av[4] = {a.x, a.y, a.z, a.w};

    float sq = 0.f, ce = 0.f, pw = 0.f;

    #pragma unroll
    for (int j = 0; j < 4; ++j) {
        const int idx = i + j;
        // MSE
        float d = pv[j] - tv[j + 1];
        sq += d * d;

        // cross-entropy via logsumexp over 3 logits
        float x0 = rows[j][0], x1 = rows[j][1], x2 = rows[j][2];
        float m  = fmaxf(x0, fmaxf(x1, x2));
        float lse = m + __logf(__expf(x0 - m) + __expf(x1 - m) + __expf(x2 - m));
        float tgt = (av[j] == 0) ? x0 : ((av[j] == 1) ? x1 : x2);
        ce += lse - tgt;

        // argmax (first-max, matches jnp.argmax)
        int pidx = 0;
        float best = x0;
        if (x1 > best) { best = x1; pidx = 1; }
        if (x2 > best) { pidx = 2; }

        float profit = 0.f;
        if (pidx == 0)      profit = (idx + 1 < NN) ? (tv[j + 2] - tv[j + 1]) : 0.f;
        else if (pidx == 2) profit = (idx > 0)      ? (tv[j + 1] - tv[j])     : 0.f;

        pw += 1.f / (1.f + __expf(-10.f * profit));
    }

    // ---- block reduction (wave-64 shuffle -> LDS) ----------------------
    #pragma unroll
    for (int off = 32; off > 0; off >>= 1) {
        sq += __shfl_down(sq, off, 64);
        ce += __shfl_down(ce, off, 64);
        pw += __shfl_down(pw, off, 64);
    }

    __shared__ float s_sq[4], s_ce[4], s_pw[4];
    const int lane = tid & 63;
    const int wid  = tid >> 6;
    if (lane == 0) { s_sq[wid] = sq; s_ce[wid] = ce; s_pw[wid] = pw; }
    __syncthreads();

    if (tid == 0) {
        bsum[bid]          = s_sq[0] + s_sq[1] + s_sq[2] + s_sq[3];
        bsum[NB + bid]     = s_ce[0] + s_ce[1] + s_ce[2] + s_ce[3];
        bsum[2 * NB + bid] = s_pw[0] + s_pw[1] + s_pw[2] + s_pw[3];
    }

    // ---- last-block-done final reduction -------------------------------
    __threadfence();                       // release bsum stores device-wide
    __shared__ int s_last;
    if (tid == 0)
        s_last = (atomicAdd(counter, 1u) == (unsigned)(NB - 1));
    __syncthreads();
    if (!s_last) return;
    __threadfence();                       // acquire: see all blocks' bsum

    double dsq = 0.0, dce = 0.0, dpw = 0.0;
    for (int k = tid; k < NB; k += TPB) {
        dsq += (double)bsum[k];
        dce += (double)bsum[NB + k];
        dpw += (double)bsum[2 * NB + k];
    }
    #pragma unroll
    for (int off = 32; off > 0; off >>= 1) {
        dsq += __shfl_down(dsq, off, 64);
        dce += __shfl_down(dce, off, 64);
        dpw += __shfl_down(dpw, off, 64);
    }
    __shared__ double d_sq[4], d_ce[4], d_pw[4];
    if (lane == 0) { d_sq[wid] = dsq; d_ce[wid] = dce; d_pw[wid] = dpw; }
    __syncthreads();

    if (tid == 0) {
        double tsq = d_sq[0] + d_sq[1] + d_sq[2] + d_sq[3];
        double tce = d_ce[0] + d_ce[1] + d_ce[2] + d_ce[3];
        double tpw = d_pw[0] + d_pw[1] + d_pw[2] + d_pw[3];
        const double inv = 1.0 / (double)NN;
        out[0] = (float)(0.7 * (tce * inv) * (tpw * inv) + 0.3 * (tsq * inv));
    }
}

extern "C" void kernel_launch(void* const* d_in, const int* in_sizes, int n_in,
                              void* d_out, int out_size, void* d_ws, size_t ws_size,
                              hipStream_t stream) {
    const float* pp = (const float*)d_in[0];   // pred_prices
    const float* pa = (const float*)d_in[1];   // pred_actions [N,3]
    const float* tp = (const float*)d_in[2];   // tgt_prices
    const int*   ta = (const int*)d_in[3];     // tgt_actions (int32)
    // d_in[4] (prices) unused by reference.

    unsigned* counter = (unsigned*)d_ws;                       // 4 B, must be 0
    float*    bsum    = (float*)((char*)d_ws + 256);           // 3*NB floats = 48 KB

    hipMemsetAsync(counter, 0, sizeof(unsigned), stream);      // ws is poisoned 0xAA
    pfl_fused<<<NB, TPB, 0, stream>>>(pp, pa, tp, ta, bsum, counter, (float*)d_out);
}

// Round 4
// 134.791 us; speedup vs baseline: 5.4142x; 5.4142x over previous
//
#include <hip/hip_runtime.h>

static constexpr int NN  = 4194304;   // N
static constexpr int NB  = 4096;      // blocks; NB * TPB * 4 rows == NN
static constexpr int TPB = 256;

// ---------------------------------------------------------------------------
// Main kernel: one group of 4 rows per thread (max TLP, 20 VGPRs, 82% occ —
// measured R3). NO device-scope fences / atomics (R3: two __threadfence()
// per block on 8 non-coherent XCDs serialized the dispatch 647 µs).
// Per-block partials -> d_ws; second launch reduces them.
// ---------------------------------------------------------------------------
__global__ __launch_bounds__(256) void pfl_main(
    const float* __restrict__ pp,   // pred_prices [N]
    const float* __restrict__ pa,   // pred_actions [N,3]
    const float* __restrict__ tp,   // tgt_prices [N]
    const int*   __restrict__ ta,   // tgt_actions [N] (int32)
    float* __restrict__ bsum)       // [3*NB] per-block partials
{
    const int tid = threadIdx.x;
    const int bid = blockIdx.x;
    const int g   = bid * TPB + tid;   // group of 4 rows
    const int i   = g * 4;

    const float4* pp4 = (const float4*)pp;
    const float4* tp4 = (const float4*)tp;
    const float4* pa4 = (const float4*)pa;
    const int4*   ta4 = (const int4*)ta;

    // ---- loads (all issued up front) -----------------------------------
    float4 p  = pp4[g];
    float4 t  = tp4[g];
    int4   a  = ta4[g];
    float4 A0 = pa4[3*g + 0];
    float4 A1 = pa4[3*g + 1];
    float4 A2 = pa4[3*g + 2];
    float tm1 = (i > 0)      ? tp[i - 1] : 0.f;   // L1 hits
    float tnx = (i + 4 < NN) ? tp[i + 4] : 0.f;

    float tv[6] = {tm1, t.x, t.y, t.z, t.w, tnx};
    float pv[4] = {p.x, p.y, p.z, p.w};
    float rows[4][3] = {{A0.x, A0.y, A0.z},
                        {A0.w, A1.x, A1.y},
                        {A1.z, A1.w, A2.x},
                        {A2.y, A2.z, A2.w}};
    int av[4] = {a.x, a.y, a.z, a.w};

    float sq = 0.f, ce = 0.f, pw = 0.f;

    #pragma unroll
    for (int j = 0; j < 4; ++j) {
        const int idx = i + j;
        // MSE
        float d = pv[j] - tv[j + 1];
        sq += d * d;

        // cross-entropy via logsumexp over 3 logits
        float x0 = rows[j][0], x1 = rows[j][1], x2 = rows[j][2];
        float m  = fmaxf(x0, fmaxf(x1, x2));
        float lse = m + __logf(__expf(x0 - m) + __expf(x1 - m) + __expf(x2 - m));
        float tgt = (av[j] == 0) ? x0 : ((av[j] == 1) ? x1 : x2);
        ce += lse - tgt;

        // argmax (first-max, matches jnp.argmax)
        int pidx = 0;
        float best = x0;
        if (x1 > best) { best = x1; pidx = 1; }
        if (x2 > best) { pidx = 2; }

        float profit = 0.f;
        if (pidx == 0)      profit = (idx + 1 < NN) ? (tv[j + 2] - tv[j + 1]) : 0.f;
        else if (pidx == 2) profit = (idx > 0)      ? (tv[j + 1] - tv[j])     : 0.f;

        pw += 1.f / (1.f + __expf(-10.f * profit));
    }

    // ---- block reduction (wave-64 shuffle -> LDS) ----------------------
    #pragma unroll
    for (int off = 32; off > 0; off >>= 1) {
        sq += __shfl_down(sq, off, 64);
        ce += __shfl_down(ce, off, 64);
        pw += __shfl_down(pw, off, 64);
    }

    __shared__ float s_sq[4], s_ce[4], s_pw[4];
    const int lane = tid & 63;
    const int wid  = tid >> 6;
    if (lane == 0) { s_sq[wid] = sq; s_ce[wid] = ce; s_pw[wid] = pw; }
    __syncthreads();

    if (tid == 0) {
        bsum[bid]          = s_sq[0] + s_sq[1] + s_sq[2] + s_sq[3];
        bsum[NB + bid]     = s_ce[0] + s_ce[1] + s_ce[2] + s_ce[3];
        bsum[2 * NB + bid] = s_pw[0] + s_pw[1] + s_pw[2] + s_pw[3];
    }
}

// ---------------------------------------------------------------------------
// Finalize: 1024 threads, float4 loads — each thread grabs one float4 from
// each of the three partial arrays (4096 floats = 1024 float4 each).
// out = 0.7 * (ce/N) * (pw/N) + 0.3 * (sq/N)
// ---------------------------------------------------------------------------
__global__ __launch_bounds__(1024) void pfl_final(const float* __restrict__ bsum,
                                                  float* __restrict__ out) {
    const int tid = threadIdx.x;
    const float4* b4 = (const float4*)bsum;
    const int Q = NB / 4;               // 1024 float4s per array

    float4 vsq = b4[tid];               // array 0: [0,   Q)
    float4 vce = b4[Q + tid];           // array 1: [Q,  2Q)
    float4 vpw = b4[2 * Q + tid];       // array 2: [2Q, 3Q)

    double sq = (double)vsq.x + vsq.y + vsq.z + vsq.w;
    double ce = (double)vce.x + vce.y + vce.z + vce.w;
    double pw = (double)vpw.x + vpw.y + vpw.z + vpw.w;

    #pragma unroll
    for (int off = 32; off > 0; off >>= 1) {
        sq += __shfl_down(sq, off, 64);
        ce += __shfl_down(ce, off, 64);
        pw += __shfl_down(pw, off, 64);
    }

    __shared__ double s_sq[16], s_ce[16], s_pw[16];
    const int lane = tid & 63;
    const int wid  = tid >> 6;
    if (lane == 0) { s_sq[wid] = sq; s_ce[wid] = ce; s_pw[wid] = pw; }
    __syncthreads();

    if (tid == 0) {
        double tsq = 0.0, tce = 0.0, tpw = 0.0;
        #pragma unroll
        for (int w = 0; w < 16; ++w) { tsq += s_sq[w]; tce += s_ce[w]; tpw += s_pw[w]; }
        const double inv = 1.0 / (double)NN;
        out[0] = (float)(0.7 * (tce * inv) * (tpw * inv) + 0.3 * (tsq * inv));
    }
}

extern "C" void kernel_launch(void* const* d_in, const int* in_sizes, int n_in,
                              void* d_out, int out_size, void* d_ws, size_t ws_size,
                              hipStream_t stream) {
    const float* pp = (const float*)d_in[0];   // pred_prices
    const float* pa = (const float*)d_in[1];   // pred_actions [N,3]
    const float* tp = (const float*)d_in[2];   // tgt_prices
    const int*   ta = (const int*)d_in[3];     // tgt_actions (int32)
    // d_in[4] (prices) unused by reference.

    float* bsum = (float*)d_ws;                // 3*NB floats = 48 KB, written not read-modify

    pfl_main<<<NB, TPB, 0, stream>>>(pp, pa, tp, ta, bsum);
    pfl_final<<<1, 1024, 0, stream>>>(bsum, (float*)d_out);
}